// Round 6
// baseline (297.016 us; speedup 1.0000x reference)
//
#include <hip/hip_runtime.h>
#include <hip/hip_bf16.h>

#define NN 100000
#define NE 500000
#define FEAT 128
#define CHN 128

#define IDX_OFF 12800000
#define EDGE_OUT_OFF 13800000
#define U_OFF 77800000

#define GRID 512
#define ETILES 1954          // ceil(NE/256): 256 edges per block-tile (4 waves x 64)
#define NTILES 782           // ceil(NN/128): 128 rows per block-tile (4 waves x 32)

#define EW_STRIDE 264        // 256 + 8 pad (bf16 elems)
#define NW_STRIDE 136        // 128 + 8 pad

typedef short bf8 __attribute__((ext_vector_type(8)));
typedef float f32x4 __attribute__((ext_vector_type(4)));

__device__ __forceinline__ unsigned cvt2(float lo, float hi) {
    __hip_bfloat162 h = __float22bfloat162_rn(make_float2(lo, hi));
    union { __hip_bfloat162 h; unsigned u; } v; v.h = h;
    return v.u;
}

__device__ __forceinline__ bf8 pack8(const float4 a, const float4 b) {
    union { bf8 v; unsigned u[4]; } r;
    r.u[0] = cvt2(a.x, a.y); r.u[1] = cvt2(a.z, a.w);
    r.u[2] = cvt2(b.x, b.y); r.u[3] = cvt2(b.z, b.w);
    return r.v;
}

__global__ __launch_bounds__(256, 2) void fused_all(
        const float* __restrict__ nf, const int* __restrict__ eidx,
        const float* __restrict__ u,
        const float* __restrict__ nW, const float* __restrict__ nbias,
        const float* __restrict__ eW, const float* __restrict__ ebias,
        float* __restrict__ out) {
    __shared__ __align__(16) unsigned short Wl[128 * EW_STRIDE];   // 66 KB, restaged per phase
    const int tid = threadIdx.x;
    const int wv = tid >> 6, l = tid & 63, l15 = l & 15, lq = l >> 4;
    const int kl = lq * 8;
    const int bid = blockIdx.x;

    // ================= phase 1: edge GEMM (all blocks) =================
    for (int i = tid * 4; i < CHN * 256; i += 256 * 4) {
        const float4 w = *(const float4*)(eW + i);
        unsigned short* p = &Wl[(i >> 8) * EW_STRIDE + (i & 255)];
        *(unsigned*)&p[0] = cvt2(w.x, w.y);
        *(unsigned*)&p[2] = cvt2(w.z, w.w);
    }
    __syncthreads();
    {
        float* oute = out + EDGE_OUT_OFF;
        for (int tile = bid; tile < ETILES; tile += GRID) {
            const int rowblk = tile * 256 + wv * 64;
            int rs[4], rd[4]; bool val[4];
#pragma unroll
            for (int s = 0; s < 4; ++s) {
                val[s] = (rowblk + s * 16) < NE;   // NE % 16 == 0: all-or-nothing per subtile
                const int e = rowblk + s * 16 + l15;
                rs[s] = val[s] ? eidx[e] : 0;
                rd[s] = val[s] ? eidx[NE + e] : 0;
            }
            f32x4 acc[4][8];
            for (int s = 0; s < 4; ++s)
                for (int n = 0; n < 8; ++n) acc[s][n] = (f32x4){0.f, 0.f, 0.f, 0.f};
#pragma unroll
            for (int t = 0; t < 4; ++t) {
                const int kb = t * 32 + kl;        // 0..127 within each half
                bf8 as_[4], ad_[4];
#pragma unroll
                for (int s = 0; s < 4; ++s) {      // 8 independent gather loads in flight
                    const float* ps = nf + (size_t)rs[s] * FEAT + kb;
                    const float* pd = nf + (size_t)rd[s] * FEAT + kb;
                    as_[s] = pack8(*(const float4*)ps, *(const float4*)(ps + 4));
                    ad_[s] = pack8(*(const float4*)pd, *(const float4*)(pd + 4));
                }
#pragma unroll
                for (int n = 0; n < 8; ++n) {
                    const bf8 wfs = *(const bf8*)&Wl[(n * 16 + l15) * EW_STRIDE + kb];
                    const bf8 wfd = *(const bf8*)&Wl[(n * 16 + l15) * EW_STRIDE + kb + 128];
#pragma unroll
                    for (int s = 0; s < 4; ++s) {
                        // swapped operands: D col = edge (l15), D row = channel (lq*4+i)
                        acc[s][n] = __builtin_amdgcn_mfma_f32_16x16x32_bf16(wfs, as_[s], acc[s][n], 0, 0, 0);
                        acc[s][n] = __builtin_amdgcn_mfma_f32_16x16x32_bf16(wfd, ad_[s], acc[s][n], 0, 0, 0);
                    }
                }
            }
#pragma unroll
            for (int s = 0; s < 4; ++s) {
                if (!val[s]) continue;
                float* base = oute + (size_t)(rowblk + s * 16 + l15) * CHN;
#pragma unroll
                for (int n = 0; n < 8; ++n) {
                    const float4 b4 = *(const float4*)(ebias + n * 16 + lq * 4);
                    float4 o;
                    o.x = acc[s][n][0] + b4.x; o.y = acc[s][n][1] + b4.y;
                    o.z = acc[s][n][2] + b4.z; o.w = acc[s][n][3] + b4.w;
                    *(float4*)(base + n * 16 + lq * 4) = o;   // 16B/lane coalesced
                }
            }
        }
    }
    __syncthreads();

    // ================= phase 2: node GEMM (all blocks) =================
    for (int i = tid * 4; i < CHN * FEAT; i += 256 * 4) {
        const float4 w = *(const float4*)(nW + i);
        unsigned short* p = &Wl[(i >> 7) * NW_STRIDE + (i & 127)];
        *(unsigned*)&p[0] = cvt2(w.x, w.y);
        *(unsigned*)&p[2] = cvt2(w.z, w.w);
    }
    __syncthreads();
    for (int tile = bid; tile < NTILES; tile += GRID) {
        const int rowblk = tile * 128 + wv * 32;
        if (rowblk >= NN) continue;                // NN % 32 == 0: full subtiles
        f32x4 acc[2][8];
        for (int s = 0; s < 2; ++s)
            for (int n = 0; n < 8; ++n) acc[s][n] = (f32x4){0.f, 0.f, 0.f, 0.f};
#pragma unroll
        for (int t = 0; t < 4; ++t) {
            const int kb = t * 32 + kl;
            bf8 a[2];
#pragma unroll
            for (int s = 0; s < 2; ++s) {
                const float* ap = nf + (size_t)(rowblk + s * 16 + l15) * FEAT + kb;
                a[s] = pack8(*(const float4*)ap, *(const float4*)(ap + 4));
            }
#pragma unroll
            for (int n = 0; n < 8; ++n) {
                const bf8 wf = *(const bf8*)&Wl[(n * 16 + l15) * NW_STRIDE + kb];
                acc[0][n] = __builtin_amdgcn_mfma_f32_16x16x32_bf16(wf, a[0], acc[0][n], 0, 0, 0);
                acc[1][n] = __builtin_amdgcn_mfma_f32_16x16x32_bf16(wf, a[1], acc[1][n], 0, 0, 0);
            }
        }
#pragma unroll
        for (int s = 0; s < 2; ++s) {
            float* base = out + (size_t)(rowblk + s * 16 + l15) * CHN;
#pragma unroll
            for (int n = 0; n < 8; ++n) {
                const float4 b4 = *(const float4*)(nbias + n * 16 + lq * 4);
                float4 o;
                o.x = acc[s][n][0] + b4.x; o.y = acc[s][n][1] + b4.y;
                o.z = acc[s][n][2] + b4.z; o.w = acc[s][n][3] + b4.w;
                *(float4*)(base + n * 16 + lq * 4) = o;
            }
        }
    }

    // ================= phase 3: misc passthroughs =================
    const int4* ei4 = (const int4*)eidx;
    float4* oi4 = (float4*)(out + IDX_OFF);
    for (int i = bid * 256 + tid; i < (2 * NE) / 4; i += GRID * 256) {
        const int4 v = ei4[i];
        oi4[i] = make_float4((float)v.x, (float)v.y, (float)v.z, (float)v.w);
    }
    if (bid == 0 && tid < CHN) out[U_OFF + tid] = u[tid];
}

extern "C" void kernel_launch(void* const* d_in, const int* in_sizes, int n_in,
                              void* d_out, int out_size, void* d_ws, size_t ws_size,
                              hipStream_t stream) {
    const float* nf   = (const float*)d_in[0];
    const int*   eidx = (const int*)d_in[1];
    const float* u    = (const float*)d_in[3];
    const float* nW   = (const float*)d_in[4];
    const float* nb   = (const float*)d_in[5];
    const float* eW   = (const float*)d_in[6];
    const float* eb   = (const float*)d_in[7];
    float* out = (float*)d_out;

    hipLaunchKernelGGL(fused_all, dim3(GRID), dim3(256), 0, stream,
                       nf, eidx, u, nW, nb, eW, eb, out);
}

// Round 7
// 182.293 us; speedup vs baseline: 1.6293x; 1.6293x over previous
//
#include <hip/hip_runtime.h>
#include <hip/hip_bf16.h>

#define NN 100000
#define NE 500000
#define FEAT 128
#define CHN 128

#define IDX_OFF 12800000
#define EDGE_OUT_OFF 13800000
#define U_OFF 77800000

#define GRID 512
#define ETILES 1954          // ceil(NE/256): 256 edges per tile (4 waves x 64)
#define NTILES 782           // ceil(NN/128): 128 rows per tile (4 waves x 32)
#define TOTAL_UNITS (ETILES + NTILES)

#define EW_STRIDE 264        // 256 + 8 pad (bf16 elems)
#define NW_STRIDE 136        // 128 + 8 pad

typedef short bf8 __attribute__((ext_vector_type(8)));
typedef float f32x4 __attribute__((ext_vector_type(4)));

__device__ __forceinline__ unsigned cvt2(float lo, float hi) {
    __hip_bfloat162 h = __float22bfloat162_rn(make_float2(lo, hi));
    union { __hip_bfloat162 h; unsigned u; } v; v.h = h;
    return v.u;
}

__device__ __forceinline__ bf8 pack8(const float4 a, const float4 b) {
    union { bf8 v; unsigned u[4]; } r;
    r.u[0] = cvt2(a.x, a.y); r.u[1] = cvt2(a.z, a.w);
    r.u[2] = cvt2(b.x, b.y); r.u[3] = cvt2(b.z, b.w);
    return r.v;
}

__global__ __launch_bounds__(256) void fused_dyn(
        const float* __restrict__ nf, const int* __restrict__ eidx,
        const float* __restrict__ u,
        const float* __restrict__ nW, const float* __restrict__ nbias,
        const float* __restrict__ eW, const float* __restrict__ ebias,
        float* __restrict__ out, int* __restrict__ counter) {
    __shared__ __align__(16) unsigned short Wl[128 * EW_STRIDE];   // 66 KB
    __shared__ int s_unit;
    const int tid = threadIdx.x;
    const int wv = tid >> 6, l = tid & 63, l15 = l & 15, lq = l >> 4;
    const int kl = lq * 8;
    const int bid = blockIdx.x;
    float* const oute = out + EDGE_OUT_OFF;

    // bias fragments for both roles (16 VGPR)
    float ebv[8], nbv[8];
#pragma unroll
    for (int n = 0; n < 8; ++n) { ebv[n] = ebias[n * 16 + l15]; nbv[n] = nbias[n * 16 + l15]; }

    // stage edge W first (all blocks begin on edge tiles)
    for (int i = tid * 4; i < CHN * 256; i += 256 * 4) {
        const float4 w = *(const float4*)(eW + i);
        unsigned short* p = &Wl[(i >> 8) * EW_STRIDE + (i & 255)];
        *(unsigned*)&p[0] = cvt2(w.x, w.y);
        *(unsigned*)&p[2] = cvt2(w.z, w.w);
    }
    bool nodeW = false;

    while (true) {
        __syncthreads();                    // protects s_unit reuse + Wl (re)stage
        if (tid == 0) s_unit = atomicAdd(counter, 1);
        __syncthreads();
        const int unit = s_unit;            // block-uniform
        if (unit >= TOTAL_UNITS) break;

        if (unit < ETILES) {
            // ================= edge tile: 256 edges =================
            const int rowblk = unit * 256 + wv * 64;
            int rs[4], rd[4]; bool val[4];
#pragma unroll
            for (int s = 0; s < 4; ++s) {
                val[s] = (rowblk + s * 16) < NE;   // NE % 16 == 0
                const int e = rowblk + s * 16 + l15;
                rs[s] = val[s] ? eidx[e] : 0;
                rd[s] = val[s] ? eidx[NE + e] : 0;
            }
            f32x4 acc[4][8];
            for (int s = 0; s < 4; ++s)
                for (int n = 0; n < 8; ++n) acc[s][n] = (f32x4){0.f, 0.f, 0.f, 0.f};
#pragma unroll
            for (int t = 0; t < 8; ++t) {
                const int kb = t * 32 + kl;        // 0..255
                const int col = kb & 127;          // t>=4 -> dst half (uniform)
                bf8 a[4];
#pragma unroll
                for (int s = 0; s < 4; ++s) {
                    const float* ap = nf + (size_t)((t < 4) ? rs[s] : rd[s]) * FEAT + col;
                    a[s] = pack8(*(const float4*)ap, *(const float4*)(ap + 4));
                }
#pragma unroll
                for (int n = 0; n < 8; ++n) {
                    const bf8 wf = *(const bf8*)&Wl[(n * 16 + l15) * EW_STRIDE + kb];
#pragma unroll
                    for (int s = 0; s < 4; ++s)
                        acc[s][n] = __builtin_amdgcn_mfma_f32_16x16x32_bf16(a[s], wf, acc[s][n], 0, 0, 0);
                }
            }
#pragma unroll
            for (int s = 0; s < 4; ++s) {
                if (!val[s]) continue;
                const int m0 = rowblk + s * 16 + lq * 4;
#pragma unroll
                for (int n = 0; n < 8; ++n)
#pragma unroll
                    for (int i = 0; i < 4; ++i)
                        oute[(size_t)(m0 + i) * CHN + n * 16 + l15] = acc[s][n][i] + ebv[n];
            }
        } else {
            if (!nodeW) {                   // one-time restage (block-uniform)
                for (int i = tid * 4; i < CHN * FEAT; i += 256 * 4) {
                    const float4 w = *(const float4*)(nW + i);
                    unsigned short* p = &Wl[(i >> 7) * NW_STRIDE + (i & 127)];
                    *(unsigned*)&p[0] = cvt2(w.x, w.y);
                    *(unsigned*)&p[2] = cvt2(w.z, w.w);
                }
                nodeW = true;
                __syncthreads();
            }
            // ================= node tile: 128 rows =================
            const int rowblk = (unit - ETILES) * 128 + wv * 32;
            if (rowblk >= NN) continue;     // NN % 32 == 0
            f32x4 acc[2][8];
            for (int s = 0; s < 2; ++s)
                for (int n = 0; n < 8; ++n) acc[s][n] = (f32x4){0.f, 0.f, 0.f, 0.f};
#pragma unroll
            for (int t = 0; t < 4; ++t) {
                const int kb = t * 32 + kl;
                bf8 a[2];
#pragma unroll
                for (int s = 0; s < 2; ++s) {
                    const float* ap = nf + (size_t)(rowblk + s * 16 + l15) * FEAT + kb;
                    a[s] = pack8(*(const float4*)ap, *(const float4*)(ap + 4));
                }
#pragma unroll
                for (int n = 0; n < 8; ++n) {
                    const bf8 wf = *(const bf8*)&Wl[(n * 16 + l15) * NW_STRIDE + kb];
                    acc[0][n] = __builtin_amdgcn_mfma_f32_16x16x32_bf16(a[0], wf, acc[0][n], 0, 0, 0);
                    acc[1][n] = __builtin_amdgcn_mfma_f32_16x16x32_bf16(a[1], wf, acc[1][n], 0, 0, 0);
                }
            }
#pragma unroll
            for (int s = 0; s < 2; ++s) {
                const int m0 = rowblk + s * 16 + lq * 4;
#pragma unroll
                for (int n = 0; n < 8; ++n)
#pragma unroll
                    for (int i = 0; i < 4; ++i)
                        out[(size_t)(m0 + i) * CHN + n * 16 + l15] = acc[s][n][i] + nbv[n];
            }
        }
    }

    // ================= misc passthroughs =================
    const int4* ei4 = (const int4*)eidx;
    float4* oi4 = (float4*)(out + IDX_OFF);
    for (int i = bid * 256 + tid; i < (2 * NE) / 4; i += GRID * 256) {
        const int4 v = ei4[i];
        oi4[i] = make_float4((float)v.x, (float)v.y, (float)v.z, (float)v.w);
    }
    if (bid == 0 && tid < CHN) out[U_OFF + tid] = u[tid];
}

extern "C" void kernel_launch(void* const* d_in, const int* in_sizes, int n_in,
                              void* d_out, int out_size, void* d_ws, size_t ws_size,
                              hipStream_t stream) {
    const float* nf   = (const float*)d_in[0];
    const int*   eidx = (const int*)d_in[1];
    const float* u    = (const float*)d_in[3];
    const float* nW   = (const float*)d_in[4];
    const float* nb   = (const float*)d_in[5];
    const float* eW   = (const float*)d_in[6];
    const float* eb   = (const float*)d_in[7];
    float* out = (float*)d_out;
    int* counter = (int*)d_ws;

    hipMemsetAsync(counter, 0, sizeof(int), stream);   // reset work counter every launch
    hipLaunchKernelGGL(fused_dyn, dim3(GRID), dim3(256), 0, stream,
                       nf, eidx, u, nW, nb, eW, eb, out, counter);
}

// Round 9
// 132.026 us; speedup vs baseline: 2.2497x; 1.3807x over previous
//
#include <hip/hip_runtime.h>
#include <hip/hip_bf16.h>

#define NN 100000
#define NE 500000
#define FEAT 128
#define CHN 128

#define IDX_OFF 12800000
#define EDGE_OUT_OFF 13800000
#define U_OFF 77800000

#define NW_STRIDE 136        // 128 + 8 pad (bf16 elems)
#define EW_STRIDE 264        // 256 + 8 pad (fallback kernel)
#define ATILES 782           // ceil(NN/128)

typedef short bf8 __attribute__((ext_vector_type(8)));
typedef float f32x4 __attribute__((ext_vector_type(4)));

__device__ __forceinline__ unsigned short f2bf(float x) {
    union { float f; unsigned u; } v; v.f = x;
    return (unsigned short)((v.u + 0x7fffu + ((v.u >> 16) & 1u)) >> 16);
}
__device__ __forceinline__ float bf2f(unsigned short x) {
    union { unsigned u; float f; } v; v.u = (unsigned)x << 16; return v.f;
}
__device__ __forceinline__ unsigned cvt2(float lo, float hi) {
    __hip_bfloat162 h = __float22bfloat162_rn(make_float2(lo, hi));
    union { __hip_bfloat162 h; unsigned u; } v; v.h = h;
    return v.u;
}
__device__ __forceinline__ bf8 pack8(const float4 a, const float4 b) {
    union { bf8 v; unsigned u[4]; } r;
    r.u[0] = cvt2(a.x, a.y); r.u[1] = cvt2(a.z, a.w);
    r.u[2] = cvt2(b.x, b.y); r.u[3] = cvt2(b.z, b.w);
    return r.v;
}

// ========== Kernel A: node GEMM + P/Q materialization + misc ==========
__global__ __launch_bounds__(256) void dense_all(
        const float* __restrict__ nf, const int* __restrict__ eidx,
        const float* __restrict__ u,
        const float* __restrict__ nW, const float* __restrict__ nbias,
        const float* __restrict__ eW, const float* __restrict__ ebias,
        float* __restrict__ out,
        unsigned short* __restrict__ P16, unsigned short* __restrict__ Q16) {
    __shared__ __align__(16) unsigned short Wl[128 * NW_STRIDE];   // 34.8 KB
    const int tid = threadIdx.x;
    const int wv = tid >> 6, l = tid & 63, l15 = l & 15, lq = l >> 4;
    const int kl = lq * 8;
    const int bid = blockIdx.x;

    const int rowblk = bid * 128 + wv * 32;
    const bool valid = rowblk < NN;                 // NN % 32 == 0: all-or-nothing per wave
    const int rbase = valid ? rowblk : 0;

    // load this wave's 32 nf rows ONCE as bf16 fragments (reused by all 3 phases)
    bf8 a[2][4];
#pragma unroll
    for (int s = 0; s < 2; ++s)
#pragma unroll
        for (int t = 0; t < 4; ++t) {
            const float* ap = nf + (size_t)(rbase + s * 16 + l15) * FEAT + t * 32 + kl;
            a[s][t] = pack8(*(const float4*)ap, *(const float4*)(ap + 4));
        }

    float nbv[8], ebv[8];
#pragma unroll
    for (int n = 0; n < 8; ++n) { nbv[n] = nbias[n * 16 + l15]; ebv[n] = ebias[n * 16 + l15]; }

    // -------- phase 0: node_out = nf @ nW^T + nb (f32) --------
    for (int i = tid * 4; i < CHN * FEAT; i += 256 * 4) {
        const float4 w = *(const float4*)(nW + i);
        unsigned short* p = &Wl[(i >> 7) * NW_STRIDE + (i & 127)];
        *(unsigned*)&p[0] = cvt2(w.x, w.y);
        *(unsigned*)&p[2] = cvt2(w.z, w.w);
    }
    __syncthreads();
    {
        f32x4 acc[2][8];
        for (int s = 0; s < 2; ++s)
            for (int n = 0; n < 8; ++n) acc[s][n] = (f32x4){0.f, 0.f, 0.f, 0.f};
#pragma unroll
        for (int t = 0; t < 4; ++t)
#pragma unroll
            for (int n = 0; n < 8; ++n) {
                const bf8 wf = *(const bf8*)&Wl[(n * 16 + l15) * NW_STRIDE + t * 32 + kl];
                acc[0][n] = __builtin_amdgcn_mfma_f32_16x16x32_bf16(a[0][t], wf, acc[0][n], 0, 0, 0);
                acc[1][n] = __builtin_amdgcn_mfma_f32_16x16x32_bf16(a[1][t], wf, acc[1][n], 0, 0, 0);
            }
        if (valid)
#pragma unroll
            for (int s = 0; s < 2; ++s) {
                const int m0 = rowblk + s * 16 + lq * 4;
#pragma unroll
                for (int n = 0; n < 8; ++n)
#pragma unroll
                    for (int i = 0; i < 4; ++i)
                        out[(size_t)(m0 + i) * CHN + n * 16 + l15] = acc[s][n][i] + nbv[n];
            }
    }
    __syncthreads();

    // -------- phase 1: P = nf @ eW[:, :128]^T + eb (bf16 -> ws) --------
    for (int i = tid * 4; i < CHN * FEAT; i += 256 * 4) {
        const int r = i >> 7, c = i & 127;
        const float4 w = *(const float4*)(eW + (size_t)r * 256 + c);
        unsigned short* p = &Wl[r * NW_STRIDE + c];
        *(unsigned*)&p[0] = cvt2(w.x, w.y);
        *(unsigned*)&p[2] = cvt2(w.z, w.w);
    }
    __syncthreads();
    {
        f32x4 acc[2][8];
        for (int s = 0; s < 2; ++s)
            for (int n = 0; n < 8; ++n) acc[s][n] = (f32x4){0.f, 0.f, 0.f, 0.f};
#pragma unroll
        for (int t = 0; t < 4; ++t)
#pragma unroll
            for (int n = 0; n < 8; ++n) {
                const bf8 wf = *(const bf8*)&Wl[(n * 16 + l15) * NW_STRIDE + t * 32 + kl];
                acc[0][n] = __builtin_amdgcn_mfma_f32_16x16x32_bf16(a[0][t], wf, acc[0][n], 0, 0, 0);
                acc[1][n] = __builtin_amdgcn_mfma_f32_16x16x32_bf16(a[1][t], wf, acc[1][n], 0, 0, 0);
            }
        if (valid)
#pragma unroll
            for (int s = 0; s < 2; ++s) {
                const int m0 = rowblk + s * 16 + lq * 4;
#pragma unroll
                for (int n = 0; n < 8; ++n)
#pragma unroll
                    for (int i = 0; i < 4; ++i)
                        P16[(size_t)(m0 + i) * CHN + n * 16 + l15] = f2bf(acc[s][n][i] + ebv[n]);
            }
    }
    __syncthreads();

    // -------- phase 2: Q = nf @ eW[:, 128:]^T (bf16 -> ws) --------
    for (int i = tid * 4; i < CHN * FEAT; i += 256 * 4) {
        const int r = i >> 7, c = i & 127;
        const float4 w = *(const float4*)(eW + (size_t)r * 256 + 128 + c);
        unsigned short* p = &Wl[r * NW_STRIDE + c];
        *(unsigned*)&p[0] = cvt2(w.x, w.y);
        *(unsigned*)&p[2] = cvt2(w.z, w.w);
    }
    __syncthreads();
    {
        f32x4 acc[2][8];
        for (int s = 0; s < 2; ++s)
            for (int n = 0; n < 8; ++n) acc[s][n] = (f32x4){0.f, 0.f, 0.f, 0.f};
#pragma unroll
        for (int t = 0; t < 4; ++t)
#pragma unroll
            for (int n = 0; n < 8; ++n) {
                const bf8 wf = *(const bf8*)&Wl[(n * 16 + l15) * NW_STRIDE + t * 32 + kl];
                acc[0][n] = __builtin_amdgcn_mfma_f32_16x16x32_bf16(a[0][t], wf, acc[0][n], 0, 0, 0);
                acc[1][n] = __builtin_amdgcn_mfma_f32_16x16x32_bf16(a[1][t], wf, acc[1][n], 0, 0, 0);
            }
        if (valid)
#pragma unroll
            for (int s = 0; s < 2; ++s) {
                const int m0 = rowblk + s * 16 + lq * 4;
#pragma unroll
                for (int n = 0; n < 8; ++n)
#pragma unroll
                    for (int i = 0; i < 4; ++i)
                        Q16[(size_t)(m0 + i) * CHN + n * 16 + l15] = f2bf(acc[s][n][i]);
            }
    }

    // -------- misc passthroughs --------
    const int4* ei4 = (const int4*)eidx;
    float4* oi4 = (float4*)(out + IDX_OFF);
    for (int i = bid * 256 + tid; i < (2 * NE) / 4; i += ATILES * 256) {
        const int4 v = ei4[i];
        oi4[i] = make_float4((float)v.x, (float)v.y, (float)v.z, (float)v.w);
    }
    if (bid == 0 && tid < CHN) out[U_OFF + tid] = u[tid];
}

// ========== Kernel B: edge_out[e] = P[src[e]] + Q[dst[e]] ==========
__global__ __launch_bounds__(256) void edge_add(
        const int* __restrict__ eidx,
        const unsigned short* __restrict__ P16, const unsigned short* __restrict__ Q16,
        float* __restrict__ out) {
    const int gid = blockIdx.x * 256 + threadIdx.x;   // 8,000,000 threads
    const int e = gid >> 4;
    const int c8 = (gid & 15) << 3;
    const int s = eidx[e], d = eidx[NE + e];
    const bf8 p = *(const bf8*)(P16 + (size_t)s * CHN + c8);
    const bf8 q = *(const bf8*)(Q16 + (size_t)d * CHN + c8);
    float* o = out + EDGE_OUT_OFF + (size_t)e * CHN + c8;
    float4 o0, o1;
    o0.x = bf2f((unsigned short)p[0]) + bf2f((unsigned short)q[0]);
    o0.y = bf2f((unsigned short)p[1]) + bf2f((unsigned short)q[1]);
    o0.z = bf2f((unsigned short)p[2]) + bf2f((unsigned short)q[2]);
    o0.w = bf2f((unsigned short)p[3]) + bf2f((unsigned short)q[3]);
    o1.x = bf2f((unsigned short)p[4]) + bf2f((unsigned short)q[4]);
    o1.y = bf2f((unsigned short)p[5]) + bf2f((unsigned short)q[5]);
    o1.z = bf2f((unsigned short)p[6]) + bf2f((unsigned short)q[6]);
    o1.w = bf2f((unsigned short)p[7]) + bf2f((unsigned short)q[7]);
    *(float4*)o = o0;
    *(float4*)(o + 4) = o1;
}

// ========== Fallback (ws too small): round-5 static-split fused ==========
#define EBLK_CNT 358
#define NBLK_CNT 154
#define FGRID (EBLK_CNT + NBLK_CNT)
#define ETILES 1954
#define NTILES 782

__global__ __launch_bounds__(256) void fused_static(
        const float* __restrict__ nf, const int* __restrict__ eidx,
        const float* __restrict__ u,
        const float* __restrict__ nW, const float* __restrict__ nbias,
        const float* __restrict__ eW, const float* __restrict__ ebias,
        float* __restrict__ out) {
    __shared__ __align__(16) unsigned short Wl[128 * EW_STRIDE];
    const int tid = threadIdx.x;
    const int wv = tid >> 6, l = tid & 63, l15 = l & 15, lq = l >> 4;
    const int kl = lq * 8;
    const int bid = blockIdx.x;

    if (bid < EBLK_CNT) {
        for (int i = tid * 4; i < CHN * 256; i += 256 * 4) {
            const float4 w = *(const float4*)(eW + i);
            unsigned short* p = &Wl[(i >> 8) * EW_STRIDE + (i & 255)];
            *(unsigned*)&p[0] = cvt2(w.x, w.y);
            *(unsigned*)&p[2] = cvt2(w.z, w.w);
        }
        __syncthreads();
        float bv[8];
#pragma unroll
        for (int n = 0; n < 8; ++n) bv[n] = ebias[n * 16 + l15];
        float* oute = out + EDGE_OUT_OFF;
        for (int tile = bid; tile < ETILES; tile += EBLK_CNT) {
            const int rowblk = tile * 256 + wv * 64;
            int rs[4], rd[4]; bool val[4];
#pragma unroll
            for (int s = 0; s < 4; ++s) {
                val[s] = (rowblk + s * 16) < NE;
                const int e = rowblk + s * 16 + l15;
                rs[s] = val[s] ? eidx[e] : 0;
                rd[s] = val[s] ? eidx[NE + e] : 0;
            }
            f32x4 acc[4][8];
            for (int s = 0; s < 4; ++s)
                for (int n = 0; n < 8; ++n) acc[s][n] = (f32x4){0.f, 0.f, 0.f, 0.f};
#pragma unroll
            for (int t = 0; t < 8; ++t) {
                const int kb = t * 32 + kl;
                const int col = kb & 127;
                bf8 a[4];
#pragma unroll
                for (int s = 0; s < 4; ++s) {
                    const float* ap = nf + (size_t)((t < 4) ? rs[s] : rd[s]) * FEAT + col;
                    a[s] = pack8(*(const float4*)ap, *(const float4*)(ap + 4));
                }
#pragma unroll
                for (int n = 0; n < 8; ++n) {
                    const bf8 wf = *(const bf8*)&Wl[(n * 16 + l15) * EW_STRIDE + kb];
#pragma unroll
                    for (int s = 0; s < 4; ++s)
                        acc[s][n] = __builtin_amdgcn_mfma_f32_16x16x32_bf16(a[s], wf, acc[s][n], 0, 0, 0);
                }
            }
#pragma unroll
            for (int s = 0; s < 4; ++s) {
                if (!val[s]) continue;
                const int m0 = rowblk + s * 16 + lq * 4;
#pragma unroll
                for (int n = 0; n < 8; ++n)
#pragma unroll
                    for (int i = 0; i < 4; ++i)
                        oute[(size_t)(m0 + i) * CHN + n * 16 + l15] = acc[s][n][i] + bv[n];
            }
        }
    } else {
        const int rb = bid - EBLK_CNT;
        for (int i = tid * 4; i < CHN * FEAT; i += 256 * 4) {
            const float4 w = *(const float4*)(nW + i);
            unsigned short* p = &Wl[(i >> 7) * NW_STRIDE + (i & 127)];
            *(unsigned*)&p[0] = cvt2(w.x, w.y);
            *(unsigned*)&p[2] = cvt2(w.z, w.w);
        }
        __syncthreads();
        float bv[8];
#pragma unroll
        for (int n = 0; n < 8; ++n) bv[n] = nbias[n * 16 + l15];
        for (int tile = rb; tile < NTILES; tile += NBLK_CNT) {
            const int rowblk = tile * 128 + wv * 32;
            if (rowblk >= NN) continue;
            f32x4 acc[2][8];
            for (int s = 0; s < 2; ++s)
                for (int n = 0; n < 8; ++n) acc[s][n] = (f32x4){0.f, 0.f, 0.f, 0.f};
#pragma unroll
            for (int t = 0; t < 4; ++t) {
                const int kb = t * 32 + kl;
                bf8 a[2];
#pragma unroll
                for (int s = 0; s < 2; ++s) {
                    const float* ap = nf + (size_t)(rowblk + s * 16 + l15) * FEAT + kb;
                    a[s] = pack8(*(const float4*)ap, *(const float4*)(ap + 4));
                }
#pragma unroll
                for (int n = 0; n < 8; ++n) {
                    const bf8 wf = *(const bf8*)&Wl[(n * 16 + l15) * NW_STRIDE + kb];
                    acc[0][n] = __builtin_amdgcn_mfma_f32_16x16x32_bf16(a[0], wf, acc[0][n], 0, 0, 0);
                    acc[1][n] = __builtin_amdgcn_mfma_f32_16x16x32_bf16(a[1], wf, acc[1][n], 0, 0, 0);
                }
            }
#pragma unroll
            for (int s = 0; s < 2; ++s) {
                const int m0 = rowblk + s * 16 + lq * 4;
#pragma unroll
                for (int n = 0; n < 8; ++n)
#pragma unroll
                    for (int i = 0; i < 4; ++i)
                        out[(size_t)(m0 + i) * CHN + n * 16 + l15] = acc[s][n][i] + bv[n];
            }
        }
        const int4* ei4 = (const int4*)eidx;
        float4* oi4 = (float4*)(out + IDX_OFF);
        for (int i = rb * 256 + tid; i < (2 * NE) / 4; i += NBLK_CNT * 256) {
            const int4 v = ei4[i];
            oi4[i] = make_float4((float)v.x, (float)v.y, (float)v.z, (float)v.w);
        }
        if (rb == 0 && tid < CHN) out[U_OFF + tid] = u[tid];
    }
}

extern "C" void kernel_launch(void* const* d_in, const int* in_sizes, int n_in,
                              void* d_out, int out_size, void* d_ws, size_t ws_size,
                              hipStream_t stream) {
    const float* nf   = (const float*)d_in[0];
    const int*   eidx = (const int*)d_in[1];
    const float* u    = (const float*)d_in[3];
    const float* nW   = (const float*)d_in[4];
    const float* nb   = (const float*)d_in[5];
    const float* eW   = (const float*)d_in[6];
    const float* eb   = (const float*)d_in[7];
    float* out = (float*)d_out;

    const size_t need = 2ull * NN * CHN * sizeof(unsigned short);   // 51.2 MB
    if (ws_size >= need) {
        unsigned short* P16 = (unsigned short*)d_ws;
        unsigned short* Q16 = P16 + (size_t)NN * CHN;
        hipLaunchKernelGGL(dense_all, dim3(ATILES), dim3(256), 0, stream,
                           nf, eidx, u, nW, nb, eW, eb, out, P16, Q16);
        hipLaunchKernelGGL(edge_add, dim3(NE * 16 / 256), dim3(256), 0, stream,
                           eidx, P16, Q16, out);
    } else {
        hipLaunchKernelGGL(fused_static, dim3(FGRID), dim3(256), 0, stream,
                           nf, eidx, u, nW, nb, eW, eb, out);
    }
}